// Round 15
// baseline (271.063 us; speedup 1.0000x reference)
//
#include <hip/hip_runtime.h>
#include <hip/hip_bf16.h>
#include <stdint.h>

typedef __attribute__((ext_vector_type(8))) short short8;
typedef __attribute__((ext_vector_type(4))) float f32x4;
typedef __attribute__((ext_vector_type(16))) float f32x16;
typedef __hip_bfloat16 bf16;

typedef __attribute__((address_space(3))) uint32_t lds_u32_t;
typedef __attribute__((address_space(1))) const uint32_t glb_u32_t;

__device__ __forceinline__ void gload_lds16(const void* g, void* l) {
  __builtin_amdgcn_global_load_lds((glb_u32_t*)g, (lds_u32_t*)l, 16, 0, 0);
}

__device__ __forceinline__ uint32_t cvt_pk_bf16(float lo, float hi_) {
  uint32_t r;
  asm volatile("v_cvt_pk_bf16_f32 %0, %1, %2" : "=v"(r) : "v"(lo), "v"(hi_));
  return r;  // low 16 = bf16(lo), high 16 = bf16(hi_)
}

// swap: new_a = {a[0:31], b[0:31]}, new_b = {a[32:63], b[32:63]}
__device__ __forceinline__ void plane32swap(uint32_t &a, uint32_t &b) {
  auto r = __builtin_amdgcn_permlane32_swap((int)a, (int)b, false, false);
  a = (uint32_t)r[0]; b = (uint32_t)r[1];
}

// ---------------- prep kernels ----------------

__global__ void conv_bf16(const float* __restrict__ in, bf16* __restrict__ outp, int n4) {
  int i = blockIdx.x * blockDim.x + threadIdx.x;
  if (i >= n4) return;
  const float4 v = ((const float4*)in)[i];
  union { ushort4 u; bf16 h[4]; } o;
  o.h[0] = __float2bfloat16(v.x); o.h[1] = __float2bfloat16(v.y);
  o.h[2] = __float2bfloat16(v.z); o.h[3] = __float2bfloat16(v.w);
  ((ushort4*)outp)[i] = o.u;
}

// W [1024][1024] f32 row-major -> WT [n][k] bf16  (4 matrices via blockIdx.z)
__global__ void transpose_w(const float* __restrict__ W0, const float* __restrict__ W1,
                            const float* __restrict__ W2, const float* __restrict__ W3,
                            bf16* __restrict__ outp) {
  const float* W = blockIdx.z == 0 ? W0 : blockIdx.z == 1 ? W1 : blockIdx.z == 2 ? W2 : W3;
  bf16* o = outp + (size_t)blockIdx.z * 1048576;
  __shared__ float t[32][33];
  int x = threadIdx.x, y0 = threadIdx.y;            // (32,8)
  int c0 = blockIdx.x * 32, r0 = blockIdx.y * 32;
#pragma unroll
  for (int i = 0; i < 4; i++)
    t[y0 + i*8][x] = W[(size_t)(r0 + y0 + i*8)*1024 + c0 + x];
  __syncthreads();
#pragma unroll
  for (int i = 0; i < 4; i++)
    o[(size_t)(c0 + y0 + i*8)*1024 + r0 + x] = __float2bfloat16(t[x][y0 + i*8]);
}

// attention_mask [B,1,S,S] int32 -> bit-packed words: bit=1 means masked (mask==0)
__global__ void maskpack(const int* __restrict__ mask, unsigned long long* __restrict__ mbits) {
  int tid = threadIdx.x;
  int lane = tid & 63, wid = tid >> 6;
  size_t word = (size_t)blockIdx.x * 4 + wid;       // 262144 words total
  int v = mask[word * 64 + lane];
  unsigned long long bits = __ballot(v == 0);
  if (lane == 0) mbits[word] = bits;
}

// ---------------- GEMM (B-transposed): C[M=8192][N=1024] = A[M][1024] * Bt[N][1024]^T ----------------
// MODE 0: write bf16 to [B,H,S,64]  (K)
// MODE 4: MODE 0 with C1 pre-scale   (Q — folds softmax 1/(8*ln2) scale into Q)
// MODE 1: write bf16 to [B,H,64,S]  (V pre-transposed)
// MODE 2: write f32 row-major + bias (final output)
template<int MODE>
__global__ void gemm_bt(const bf16* __restrict__ A, const bf16* __restrict__ Bt,
                        void* __restrict__ Out, const float* __restrict__ bias) {
  const int tid = threadIdx.x;
  const int lane = tid & 63, wid = tid >> 6;
  const int g = lane >> 4, c = lane & 15;
  const int m0 = blockIdx.x * 128, n0 = blockIdx.y * 128;
  const int wm = wid >> 1, wn = wid & 1;
  __shared__ bf16 As[128 * 64];
  __shared__ bf16 Bs[128 * 64];
  f32x4 acc[4][4] = {};
  for (int k0 = 0; k0 < 1024; k0 += 64) {
#pragma unroll
    for (int i = 0; i < 4; i++) {
      int chunk = wid * 4 + i;          // 16 chunks of 1KB per matrix
      int idx = chunk * 64 + lane;      // 16B unit index
      int row = idx >> 3, u = idx & 7;  // 128B rows, 8 units each
      int koff = k0 + ((u ^ (row & 7)) * 8);   // pre-swizzled source (rule #21)
      gload_lds16(A  + (size_t)(m0 + row) * 1024 + koff, As + chunk * 512);
      gload_lds16(Bt + (size_t)(n0 + row) * 1024 + koff, Bs + chunk * 512);
    }
    __syncthreads();
#pragma unroll
    for (int kk = 0; kk < 2; kk++) {
      short8 af[4], bf_[4];
#pragma unroll
      for (int f = 0; f < 4; f++) {
        int ra = wm * 64 + f * 16 + c;
        af[f]  = *(const short8*)(As + ra * 64 + (((kk * 4 + g) ^ (ra & 7)) * 8));
        int rb = wn * 64 + f * 16 + c;
        bf_[f] = *(const short8*)(Bs + rb * 64 + (((kk * 4 + g) ^ (rb & 7)) * 8));
      }
#pragma unroll
      for (int fm = 0; fm < 4; fm++)
#pragma unroll
        for (int fn = 0; fn < 4; fn++)
          acc[fm][fn] = __builtin_amdgcn_mfma_f32_16x16x32_bf16(af[fm], bf_[fn], acc[fm][fn], 0, 0, 0);
    }
    __syncthreads();
  }
#pragma unroll
  for (int fm = 0; fm < 4; fm++) {
#pragma unroll
    for (int fn = 0; fn < 4; fn++) {
      int gn = n0 + wn * 64 + fn * 16 + c;
#pragma unroll
      for (int r = 0; r < 4; r++) {
        int gm = m0 + wm * 64 + fm * 16 + g * 4 + r;
        float v = acc[fm][fn][r];
        if constexpr (MODE == 2) {
          ((float*)Out)[(size_t)gm * 1024 + gn] = v + bias[gn];
        } else if constexpr (MODE == 0 || MODE == 4) {
          if constexpr (MODE == 4) v *= 0.18033688011112042f;  // (1/8)*log2(e)
          int b = gm >> 11, s = gm & 2047, hh = gn >> 6, d = gn & 63;
          ((bf16*)Out)[(((size_t)b * 16 + hh) * 2048 + s) * 64 + d] = __float2bfloat16(v);
        } else {
          int b = gm >> 11, s = gm & 2047, hh = gn >> 6, d = gn & 63;
          ((bf16*)Out)[(((size_t)b * 16 + hh) * 64 + d) * 2048 + s] = __float2bfloat16(v);
        }
      }
    }
  }
}

// ---------------- flash attention (32x32 MFMA, swapped QK^T, T15 PV-deferral) ----------------
// grid 1024, 256 threads = 4 waves, wave owns 32 q-rows. KT=64.
// LDS: K 2-buf + V 3-buf = 40KB. Per tile: QKT(t) -> PV(t-1) [MFMA cluster] ->
// softmax(t) [VALU, overlaps in-flight MFMAs] -> paP=pa(t) -> accL ones-MFMA
// (OFF-cluster; row-sum on the idle MFMA pipe, consumed 1 tile later) -> barrier.
// STATIC-BOUND softmax (scores pre-scaled by C1 in the Q projection): P = exp2(s'),
// s' in [-8.2, 8.2] typ — no overflow, constant softmax shift cancels in O/l.
// Masked P zeroed exactly post-exp (sbfe keep-mask).
__global__ __launch_bounds__(256, 4) void attn_kernel(
    const bf16* __restrict__ Qb, const bf16* __restrict__ Kb, const bf16* __restrict__ Vt,
    const unsigned long long* __restrict__ mbits, bf16* __restrict__ ctx) {
  const int tid = threadIdx.x;
  const int lane = tid & 63, wid = tid >> 6;
  const int c5 = lane & 31, hi = lane >> 5;
  const int sid = blockIdx.x;
  const int xcd = sid & 7, idx = sid >> 3;          // 128 blocks per XCD
  const int bh = xcd * 8 + (idx >> 4);              // 8 bh clustered per XCD
  const int qb0 = (idx & 15) * 128 + wid * 32;
  const int b = bh >> 4, h = bh & 15;
  __shared__ bf16 Ks[2][64 * 64];       // [key][d], XOR-swizzled rows
  __shared__ bf16 Vs[3][64 * 64];       // V^T tile [dh][key], XOR-swizzled rows
  const bf16* Qp = Qb + (size_t)bh * 2048 * 64;
  const bf16* Kp = Kb + (size_t)bh * 2048 * 64;
  const bf16* Vp = Vt + (size_t)bh * 64 * 2048;
  const unsigned long long* mrow = mbits + ((size_t)b * 2048 + qb0 + c5) * 32;

  auto stage_k = [&](int kt, int sk) {
#pragma unroll
    for (int i = 0; i < 2; i++) {
      int chunk = wid * 2 + i;                      // 8 chunks x 1KB
      int idx2 = chunk * 64 + lane;
      int row = idx2 >> 3, u = idx2 & 7;
      gload_lds16(Kp + (size_t)(kt * 64 + row) * 64 + ((u ^ (row & 7)) * 8), &Ks[sk][chunk * 512]);
    }
  };
  auto stage_v = [&](int kt, int sv) {
#pragma unroll
    for (int i = 0; i < 2; i++) {
      int chunk = wid * 2 + i;
      int idx2 = chunk * 64 + lane;
      int row = idx2 >> 3, u = idx2 & 7;
      gload_lds16(Vp + (size_t)row * 2048 + kt * 64 + ((u ^ (row & 7)) * 8), &Vs[sv][chunk * 512]);
    }
  };

  // Q as B-frag: col q = c5, k(d) = ks*16 + hi*8 + j   (Q carries the C1 scale)
  short8 qf[4];
#pragma unroll
  for (int ks = 0; ks < 4; ks++)
    qf[ks] = *(const short8*)(Qp + (size_t)(qb0 + c5) * 64 + ks * 16 + hi * 8);

  // all-ones bf16 B-frag for the row-sum MFMA
  short8 onesf;
#pragma unroll
  for (int j = 0; j < 8; j++) onesf[j] = (short)0x3F80;

  f32x16 Oacc0 = {}, Oacc1 = {}, accL = {};
  short8 paP[4];                         // pa of previous tile (static indexing only)

  unsigned long long mwC, mwN;
  stage_k(0, 0);
  stage_v(0, 0);
  mwC = mrow[0];
  __syncthreads();   // drains tile-0 staging

  int sv = 0, svp = 2;                   // V buf of tile t, tile t-1
  for (int kt = 0; kt < 32; kt++) {
    const int sk = kt & 1;
    const int svn = (sv == 2) ? 0 : sv + 1;
    if (kt < 31) { stage_k(kt + 1, sk ^ 1); stage_v(kt + 1, svn); }
    mwN = mrow[(kt + 1) & 31];

    // ---- S'^T = K · Q'^T : lane holds q = c5; keys (reg&3)+8*(reg>>2)+4*hi+32*half ----
    f32x16 s0 = {}, s1 = {};
    __builtin_amdgcn_s_setprio(1);
#pragma unroll
    for (int ks = 0; ks < 4; ks++) {
      short8 aK0 = *(const short8*)(&Ks[sk][(c5)      * 64 + (((ks * 2 + hi) ^ (c5 & 7)) * 8)]);
      short8 aK1 = *(const short8*)(&Ks[sk][(32 + c5) * 64 + (((ks * 2 + hi) ^ (c5 & 7)) * 8)]);
      s0 = __builtin_amdgcn_mfma_f32_32x32x16_bf16(aK0, qf[ks], s0, 0, 0, 0);
      s1 = __builtin_amdgcn_mfma_f32_32x32x16_bf16(aK1, qf[ks], s1, 0, 0, 0);
    }
    // ---- PV(t-1): MFMA pipe chews this while softmax(t) runs on VALU ----
    if (kt > 0) {
#pragma unroll
      for (int ks = 0; ks < 4; ks++) {
        short8 bV0 = *(const short8*)(&Vs[svp][(c5)      * 64 + (((ks * 2 + hi) ^ (c5 & 7)) * 8)]);
        short8 bV1 = *(const short8*)(&Vs[svp][(32 + c5) * 64 + (((ks * 2 + hi) ^ (c5 & 7)) * 8)]);
        Oacc0 = __builtin_amdgcn_mfma_f32_32x32x16_bf16(paP[ks], bV0, Oacc0, 0, 0, 0);
        Oacc1 = __builtin_amdgcn_mfma_f32_32x32x16_bf16(paP[ks], bV1, Oacc1, 0, 0, 0);
      }
    }
    __builtin_amdgcn_s_setprio(0);
    // ---- P = v_exp(s'); zero masked (sbfe keep-mask); pack ----
    const uint32_t nlo = ~(((uint32_t)mwC)         >> (4 * hi));
    const uint32_t nhi = ~(((uint32_t)(mwC >> 32)) >> (4 * hi));
    uint32_t pk0[8], pk1[8];
#pragma unroll
    for (int r8 = 0; r8 < 8; r8++) {
      const int rA = 2 * r8, rB = 2 * r8 + 1;
      const int pA = (rA & 3) + 8 * (rA >> 2), pB = (rB & 3) + 8 * (rB >> 2);
      float a0 = __builtin_amdgcn_exp2f(s0[rA]);
      float a1 = __builtin_amdgcn_exp2f(s0[rB]);
      float b0 = __builtin_amdgcn_exp2f(s1[rA]);
      float b1 = __builtin_amdgcn_exp2f(s1[rB]);
      a0 = __uint_as_float(__float_as_uint(a0) & (uint32_t)__builtin_amdgcn_sbfe(nlo, pA, 1));
      a1 = __uint_as_float(__float_as_uint(a1) & (uint32_t)__builtin_amdgcn_sbfe(nlo, pB, 1));
      b0 = __uint_as_float(__float_as_uint(b0) & (uint32_t)__builtin_amdgcn_sbfe(nhi, pA, 1));
      b1 = __uint_as_float(__float_as_uint(b1) & (uint32_t)__builtin_amdgcn_sbfe(nhi, pB, 1));
      pk0[r8] = cvt_pk_bf16(a0, a1);
      pk1[r8] = cvt_pk_bf16(b0, b1);
    }
    // ---- in-register relayout to PV A-frags (overwrite paP after PV consumed it) ----
#pragma unroll
    for (int ks = 0; ks < 4; ks++) {
      const int e0 = 2 * ((2 * ks) & 3);      // 0,4,0,4
      const int e1 = 2 * ((2 * ks + 1) & 3);  // 2,6,2,6
      uint32_t w0, w1, w2, w3;
      if (ks < 2) { w0 = pk0[e0];     w2 = pk0[e1];
                    w1 = pk0[e0 + 1]; w3 = pk0[e1 + 1]; }
      else        { w0 = pk1[e0];     w2 = pk1[e1];
                    w1 = pk1[e0 + 1]; w3 = pk1[e1 + 1]; }
      plane32swap(w0, w2);
      plane32swap(w1, w3);
      union { uint32_t u[4]; short8 s; } pu;
      pu.u[0] = w0; pu.u[1] = w1; pu.u[2] = w2; pu.u[3] = w3;
      paP[ks] = pu.s;
    }
    // ---- row-sum of THIS tile's P on the MFMA pipe (off-cluster; consumed next tile) ----
#pragma unroll
    for (int ks = 0; ks < 4; ks++)
      accL = __builtin_amdgcn_mfma_f32_32x32x16_bf16(paP[ks], onesf, accL, 0, 0, 0);
    mwC = mwN;
    svp = sv; sv = svn;
    __syncthreads();   // implicit vmcnt(0): drains tile kt+1 staging (hidden under this tile)
  }
  // ---- epilogue: PV(31) from Vs[svp] (accL already includes tile 31) ----
#pragma unroll
  for (int ks = 0; ks < 4; ks++) {
    short8 bV0 = *(const short8*)(&Vs[svp][(c5)      * 64 + (((ks * 2 + hi) ^ (c5 & 7)) * 8)]);
    short8 bV1 = *(const short8*)(&Vs[svp][(32 + c5) * 64 + (((ks * 2 + hi) ^ (c5 & 7)) * 8)]);
    Oacc0 = __builtin_amdgcn_mfma_f32_32x32x16_bf16(paP[ks], bV0, Oacc0, 0, 0, 0);
    Oacc1 = __builtin_amdgcn_mfma_f32_32x32x16_bf16(paP[ks], bV1, Oacc1, 0, 0, 0);
  }
  // ---- finalize: normalize by accL (row-sum, same reg<->qrow layout as Oacc) ----
#pragma unroll
  for (int reg = 0; reg < 16; reg++) {
    const int qrow = (reg & 3) + 8 * (reg >> 2) + 4 * hi;
    float linv = __builtin_amdgcn_rcpf(accL[reg]);
    size_t base = ((size_t)b * 2048 + qb0 + qrow) * 1024 + h * 64;
    ctx[base + c5]      = __float2bfloat16(Oacc0[reg] * linv);
    ctx[base + 32 + c5] = __float2bfloat16(Oacc1[reg] * linv);
  }
}

// ---------------- launch ----------------

extern "C" void kernel_launch(void* const* d_in, const int* in_sizes, int n_in,
                              void* d_out, int out_size, void* d_ws, size_t ws_size,
                              hipStream_t stream) {
  const float* x  = (const float*)d_in[0];
  const float* y  = (const float*)d_in[1];
  const float* Wq = (const float*)d_in[2];
  const float* Wk = (const float*)d_in[3];
  const float* Wv = (const float*)d_in[4];
  const float* Wo = (const float*)d_in[5];
  const float* bo = (const float*)d_in[6];
  const int* amask = (const int*)d_in[7];
  float* out = (float*)d_out;

  char* ws = (char*)d_ws;
  bf16* xb = (bf16*)ws;                              // 16 MB  (later reused as ctx)
  bf16* yb = (bf16*)(ws + 16777216);                 // 16 MB
  bf16* WT = (bf16*)(ws + 33554432);                 // 4 x 2 MB, order q,k,v,o
  bf16* Qb = (bf16*)(ws + 41943040);                 // 16 MB  [B,H,S,64]  (C1-scaled)
  bf16* Kb = (bf16*)(ws + 58720256);                 // 16 MB  [B,H,S,64]
  bf16* Vt = (bf16*)(ws + 75497472);                 // 16 MB  [B,H,64,S]
  unsigned long long* mbits = (unsigned long long*)(ws + 92274688);  // 2 MB
  bf16* ctx = xb;  // alias: xb dead after K projection

  conv_bf16<<<8192, 256, 0, stream>>>(x, xb, 2097152);
  conv_bf16<<<8192, 256, 0, stream>>>(y, yb, 2097152);
  transpose_w<<<dim3(32, 32, 4), dim3(32, 8), 0, stream>>>(Wq, Wk, Wv, Wo, WT);
  maskpack<<<65536, 256, 0, stream>>>(amask, mbits);

  dim3 gg(64, 8);
  gemm_bt<4><<<gg, 256, 0, stream>>>(xb, WT + 0 * 1048576, Qb, nullptr);  // Q (C1-scaled)
  gemm_bt<0><<<gg, 256, 0, stream>>>(xb, WT + 1 * 1048576, Kb, nullptr);  // K
  gemm_bt<1><<<gg, 256, 0, stream>>>(yb, WT + 2 * 1048576, Vt, nullptr);  // V^T

  attn_kernel<<<1024, 256, 0, stream>>>(Qb, Kb, Vt, mbits, ctx);

  gemm_bt<2><<<gg, 256, 0, stream>>>(ctx, WT + 3 * 1048576, out, bo);
}

// Round 16
// 244.347 us; speedup vs baseline: 1.1093x; 1.1093x over previous
//
#include <hip/hip_runtime.h>
#include <hip/hip_bf16.h>
#include <stdint.h>

typedef __attribute__((ext_vector_type(8))) short short8;
typedef __attribute__((ext_vector_type(4))) float f32x4;
typedef __attribute__((ext_vector_type(16))) float f32x16;
typedef __hip_bfloat16 bf16;

typedef __attribute__((address_space(3))) uint32_t lds_u32_t;
typedef __attribute__((address_space(1))) const uint32_t glb_u32_t;

__device__ __forceinline__ void gload_lds16(const void* g, void* l) {
  __builtin_amdgcn_global_load_lds((glb_u32_t*)g, (lds_u32_t*)l, 16, 0, 0);
}

__device__ __forceinline__ uint32_t cvt_pk_bf16(float lo, float hi_) {
  uint32_t r;
  asm volatile("v_cvt_pk_bf16_f32 %0, %1, %2" : "=v"(r) : "v"(lo), "v"(hi_));
  return r;  // low 16 = bf16(lo), high 16 = bf16(hi_)
}

// swap: new_a = {a[0:31], b[0:31]}, new_b = {a[32:63], b[32:63]}
__device__ __forceinline__ void plane32swap(uint32_t &a, uint32_t &b) {
  auto r = __builtin_amdgcn_permlane32_swap((int)a, (int)b, false, false);
  a = (uint32_t)r[0]; b = (uint32_t)r[1];
}

// ---------------- prep kernels ----------------

__global__ void conv_bf16(const float* __restrict__ in, bf16* __restrict__ outp, int n4) {
  int i = blockIdx.x * blockDim.x + threadIdx.x;
  if (i >= n4) return;
  const float4 v = ((const float4*)in)[i];
  union { ushort4 u; bf16 h[4]; } o;
  o.h[0] = __float2bfloat16(v.x); o.h[1] = __float2bfloat16(v.y);
  o.h[2] = __float2bfloat16(v.z); o.h[3] = __float2bfloat16(v.w);
  ((ushort4*)outp)[i] = o.u;
}

// W [1024][1024] f32 row-major -> WT [n][k] bf16  (4 matrices via blockIdx.z)
__global__ void transpose_w(const float* __restrict__ W0, const float* __restrict__ W1,
                            const float* __restrict__ W2, const float* __restrict__ W3,
                            bf16* __restrict__ outp) {
  const float* W = blockIdx.z == 0 ? W0 : blockIdx.z == 1 ? W1 : blockIdx.z == 2 ? W2 : W3;
  bf16* o = outp + (size_t)blockIdx.z * 1048576;
  __shared__ float t[32][33];
  int x = threadIdx.x, y0 = threadIdx.y;            // (32,8)
  int c0 = blockIdx.x * 32, r0 = blockIdx.y * 32;
#pragma unroll
  for (int i = 0; i < 4; i++)
    t[y0 + i*8][x] = W[(size_t)(r0 + y0 + i*8)*1024 + c0 + x];
  __syncthreads();
#pragma unroll
  for (int i = 0; i < 4; i++)
    o[(size_t)(c0 + y0 + i*8)*1024 + r0 + x] = __float2bfloat16(t[x][y0 + i*8]);
}

// attention_mask [B,1,S,S] int32 -> bit-packed words: bit=1 means masked (mask==0)
__global__ void maskpack(const int* __restrict__ mask, unsigned long long* __restrict__ mbits) {
  int tid = threadIdx.x;
  int lane = tid & 63, wid = tid >> 6;
  size_t word = (size_t)blockIdx.x * 4 + wid;       // 262144 words total
  int v = mask[word * 64 + lane];
  unsigned long long bits = __ballot(v == 0);
  if (lane == 0) mbits[word] = bits;
}

// ---------------- GEMM (B-transposed): C[M=8192][N=1024] = A[M][1024] * Bt[N][1024]^T ----------------
// MODE 0: write bf16 to [B,H,S,64]  (K)
// MODE 4: MODE 0 with C1 pre-scale   (Q — folds softmax 1/(8*ln2) scale into Q)
// MODE 1: write bf16 to [B,H,64,S]  (V pre-transposed)
// MODE 2: write f32 row-major + bias (final output)
template<int MODE>
__global__ void gemm_bt(const bf16* __restrict__ A, const bf16* __restrict__ Bt,
                        void* __restrict__ Out, const float* __restrict__ bias) {
  const int tid = threadIdx.x;
  const int lane = tid & 63, wid = tid >> 6;
  const int g = lane >> 4, c = lane & 15;
  const int m0 = blockIdx.x * 128, n0 = blockIdx.y * 128;
  const int wm = wid >> 1, wn = wid & 1;
  __shared__ bf16 As[128 * 64];
  __shared__ bf16 Bs[128 * 64];
  f32x4 acc[4][4] = {};
  for (int k0 = 0; k0 < 1024; k0 += 64) {
#pragma unroll
    for (int i = 0; i < 4; i++) {
      int chunk = wid * 4 + i;          // 16 chunks of 1KB per matrix
      int idx = chunk * 64 + lane;      // 16B unit index
      int row = idx >> 3, u = idx & 7;  // 128B rows, 8 units each
      int koff = k0 + ((u ^ (row & 7)) * 8);   // pre-swizzled source (rule #21)
      gload_lds16(A  + (size_t)(m0 + row) * 1024 + koff, As + chunk * 512);
      gload_lds16(Bt + (size_t)(n0 + row) * 1024 + koff, Bs + chunk * 512);
    }
    __syncthreads();
#pragma unroll
    for (int kk = 0; kk < 2; kk++) {
      short8 af[4], bf_[4];
#pragma unroll
      for (int f = 0; f < 4; f++) {
        int ra = wm * 64 + f * 16 + c;
        af[f]  = *(const short8*)(As + ra * 64 + (((kk * 4 + g) ^ (ra & 7)) * 8));
        int rb = wn * 64 + f * 16 + c;
        bf_[f] = *(const short8*)(Bs + rb * 64 + (((kk * 4 + g) ^ (rb & 7)) * 8));
      }
#pragma unroll
      for (int fm = 0; fm < 4; fm++)
#pragma unroll
        for (int fn = 0; fn < 4; fn++)
          acc[fm][fn] = __builtin_amdgcn_mfma_f32_16x16x32_bf16(af[fm], bf_[fn], acc[fm][fn], 0, 0, 0);
    }
    __syncthreads();
  }
#pragma unroll
  for (int fm = 0; fm < 4; fm++) {
#pragma unroll
    for (int fn = 0; fn < 4; fn++) {
      int gn = n0 + wn * 64 + fn * 16 + c;
#pragma unroll
      for (int r = 0; r < 4; r++) {
        int gm = m0 + wm * 64 + fm * 16 + g * 4 + r;
        float v = acc[fm][fn][r];
        if constexpr (MODE == 2) {
          ((float*)Out)[(size_t)gm * 1024 + gn] = v + bias[gn];
        } else if constexpr (MODE == 0 || MODE == 4) {
          if constexpr (MODE == 4) v *= 0.18033688011112042f;  // (1/8)*log2(e)
          int b = gm >> 11, s = gm & 2047, hh = gn >> 6, d = gn & 63;
          ((bf16*)Out)[(((size_t)b * 16 + hh) * 2048 + s) * 64 + d] = __float2bfloat16(v);
        } else {
          int b = gm >> 11, s = gm & 2047, hh = gn >> 6, d = gn & 63;
          ((bf16*)Out)[(((size_t)b * 16 + hh) * 64 + d) * 2048 + s] = __float2bfloat16(v);
        }
      }
    }
  }
}

// ---------------- flash attention (32x32 MFMA, swapped QK^T, T15 PV-deferral) ----------------
// grid 1024, 256 threads = 4 waves, wave owns 32 q-rows. KT=64.
// LDS: K 2-buf + V 3-buf = 40KB. Per tile: QKT(t) -> PV(t-1) [MFMA] -> softmax(t)
// [VALU overlaps in-flight MFMAs] -> paP=pa(t) -> barrier.
// Softmax: Q carries the C1=(1/8)log2(e) scale (folded in projection, MODE 4), so
// P = exp2(raw QK^T register) directly — no fma, no shift (s' in [-8.2,8.2] typ;
// constant softmax shift cancels in O/l). Masked P zeroed exactly post-exp (sbfe).
// lsum on VALU + shuffle finalize (ones-MFMA variant twice-refuted: R13 +12us, R15 +25us).
__global__ __launch_bounds__(256, 4) void attn_kernel(
    const bf16* __restrict__ Qb, const bf16* __restrict__ Kb, const bf16* __restrict__ Vt,
    const unsigned long long* __restrict__ mbits, bf16* __restrict__ ctx) {
  const int tid = threadIdx.x;
  const int lane = tid & 63, wid = tid >> 6;
  const int c5 = lane & 31, hi = lane >> 5;
  const int sid = blockIdx.x;
  const int xcd = sid & 7, idx = sid >> 3;          // 128 blocks per XCD
  const int bh = xcd * 8 + (idx >> 4);              // 8 bh clustered per XCD
  const int qb0 = (idx & 15) * 128 + wid * 32;
  const int b = bh >> 4, h = bh & 15;
  __shared__ bf16 Ks[2][64 * 64];       // [key][d], XOR-swizzled rows
  __shared__ bf16 Vs[3][64 * 64];       // V^T tile [dh][key], XOR-swizzled rows
  const bf16* Qp = Qb + (size_t)bh * 2048 * 64;
  const bf16* Kp = Kb + (size_t)bh * 2048 * 64;
  const bf16* Vp = Vt + (size_t)bh * 64 * 2048;
  const unsigned long long* mrow = mbits + ((size_t)b * 2048 + qb0 + c5) * 32;

  auto stage_k = [&](int kt, int sk) {
#pragma unroll
    for (int i = 0; i < 2; i++) {
      int chunk = wid * 2 + i;                      // 8 chunks x 1KB
      int idx2 = chunk * 64 + lane;
      int row = idx2 >> 3, u = idx2 & 7;
      gload_lds16(Kp + (size_t)(kt * 64 + row) * 64 + ((u ^ (row & 7)) * 8), &Ks[sk][chunk * 512]);
    }
  };
  auto stage_v = [&](int kt, int sv) {
#pragma unroll
    for (int i = 0; i < 2; i++) {
      int chunk = wid * 2 + i;
      int idx2 = chunk * 64 + lane;
      int row = idx2 >> 3, u = idx2 & 7;
      gload_lds16(Vp + (size_t)row * 2048 + kt * 64 + ((u ^ (row & 7)) * 8), &Vs[sv][chunk * 512]);
    }
  };

  // Q as B-frag: col q = c5, k(d) = ks*16 + hi*8 + j   (Q carries the C1 scale)
  short8 qf[4];
#pragma unroll
  for (int ks = 0; ks < 4; ks++)
    qf[ks] = *(const short8*)(Qp + (size_t)(qb0 + c5) * 64 + ks * 16 + hi * 8);

  f32x16 Oacc0 = {}, Oacc1 = {};
  float lrun = 0.f;
  short8 paP[4];                         // pa of previous tile (static indexing only)

  unsigned long long mwC, mwN;
  stage_k(0, 0);
  stage_v(0, 0);
  mwC = mrow[0];
  __syncthreads();   // drains tile-0 staging

  int sv = 0, svp = 2;                   // V buf of tile t, tile t-1
  for (int kt = 0; kt < 32; kt++) {
    const int sk = kt & 1;
    const int svn = (sv == 2) ? 0 : sv + 1;
    if (kt < 31) { stage_k(kt + 1, sk ^ 1); stage_v(kt + 1, svn); }
    mwN = mrow[(kt + 1) & 31];

    // ---- S'^T = K · Q'^T : lane holds q = c5; keys (reg&3)+8*(reg>>2)+4*hi+32*half ----
    f32x16 s0 = {}, s1 = {};
    __builtin_amdgcn_s_setprio(1);
#pragma unroll
    for (int ks = 0; ks < 4; ks++) {
      short8 aK0 = *(const short8*)(&Ks[sk][(c5)      * 64 + (((ks * 2 + hi) ^ (c5 & 7)) * 8)]);
      short8 aK1 = *(const short8*)(&Ks[sk][(32 + c5) * 64 + (((ks * 2 + hi) ^ (c5 & 7)) * 8)]);
      s0 = __builtin_amdgcn_mfma_f32_32x32x16_bf16(aK0, qf[ks], s0, 0, 0, 0);
      s1 = __builtin_amdgcn_mfma_f32_32x32x16_bf16(aK1, qf[ks], s1, 0, 0, 0);
    }
    // ---- PV(t-1): MFMA pipe chews this while softmax(t) runs on VALU ----
    if (kt > 0) {
#pragma unroll
      for (int ks = 0; ks < 4; ks++) {
        short8 bV0 = *(const short8*)(&Vs[svp][(c5)      * 64 + (((ks * 2 + hi) ^ (c5 & 7)) * 8)]);
        short8 bV1 = *(const short8*)(&Vs[svp][(32 + c5) * 64 + (((ks * 2 + hi) ^ (c5 & 7)) * 8)]);
        Oacc0 = __builtin_amdgcn_mfma_f32_32x32x16_bf16(paP[ks], bV0, Oacc0, 0, 0, 0);
        Oacc1 = __builtin_amdgcn_mfma_f32_32x32x16_bf16(paP[ks], bV1, Oacc1, 0, 0, 0);
      }
    }
    __builtin_amdgcn_s_setprio(0);
    // ---- P = v_exp(s'); zero masked (sbfe keep-mask); pack ----
    const uint32_t nlo = ~(((uint32_t)mwC)         >> (4 * hi));
    const uint32_t nhi = ~(((uint32_t)(mwC >> 32)) >> (4 * hi));
    uint32_t pk0[8], pk1[8];
    float lsum = 0.f;
#pragma unroll
    for (int r8 = 0; r8 < 8; r8++) {
      const int rA = 2 * r8, rB = 2 * r8 + 1;
      const int pA = (rA & 3) + 8 * (rA >> 2), pB = (rB & 3) + 8 * (rB >> 2);
      float a0 = __builtin_amdgcn_exp2f(s0[rA]);
      float a1 = __builtin_amdgcn_exp2f(s0[rB]);
      float b0 = __builtin_amdgcn_exp2f(s1[rA]);
      float b1 = __builtin_amdgcn_exp2f(s1[rB]);
      a0 = __uint_as_float(__float_as_uint(a0) & (uint32_t)__builtin_amdgcn_sbfe(nlo, pA, 1));
      a1 = __uint_as_float(__float_as_uint(a1) & (uint32_t)__builtin_amdgcn_sbfe(nlo, pB, 1));
      b0 = __uint_as_float(__float_as_uint(b0) & (uint32_t)__builtin_amdgcn_sbfe(nhi, pA, 1));
      b1 = __uint_as_float(__float_as_uint(b1) & (uint32_t)__builtin_amdgcn_sbfe(nhi, pB, 1));
      lsum += (a0 + a1) + (b0 + b1);
      pk0[r8] = cvt_pk_bf16(a0, a1);
      pk1[r8] = cvt_pk_bf16(b0, b1);
    }
    lrun += lsum;
    // ---- in-register relayout to PV A-frags (overwrite paP after PV consumed it) ----
#pragma unroll
    for (int ks = 0; ks < 4; ks++) {
      const int e0 = 2 * ((2 * ks) & 3);      // 0,4,0,4
      const int e1 = 2 * ((2 * ks + 1) & 3);  // 2,6,2,6
      uint32_t w0, w1, w2, w3;
      if (ks < 2) { w0 = pk0[e0];     w2 = pk0[e1];
                    w1 = pk0[e0 + 1]; w3 = pk0[e1 + 1]; }
      else        { w0 = pk1[e0];     w2 = pk1[e1];
                    w1 = pk1[e0 + 1]; w3 = pk1[e1 + 1]; }
      plane32swap(w0, w2);
      plane32swap(w1, w3);
      union { uint32_t u[4]; short8 s; } pu;
      pu.u[0] = w0; pu.u[1] = w1; pu.u[2] = w2; pu.u[3] = w3;
      paP[ks] = pu.s;
    }
    mwC = mwN;
    svp = sv; sv = svn;
    __syncthreads();   // implicit vmcnt(0): drains tile kt+1 staging (hidden under this tile)
  }
  // ---- epilogue: PV(31) from Vs[svp] ----
#pragma unroll
  for (int ks = 0; ks < 4; ks++) {
    short8 bV0 = *(const short8*)(&Vs[svp][(c5)      * 64 + (((ks * 2 + hi) ^ (c5 & 7)) * 8)]);
    short8 bV1 = *(const short8*)(&Vs[svp][(32 + c5) * 64 + (((ks * 2 + hi) ^ (c5 & 7)) * 8)]);
    Oacc0 = __builtin_amdgcn_mfma_f32_32x32x16_bf16(paP[ks], bV0, Oacc0, 0, 0, 0);
    Oacc1 = __builtin_amdgcn_mfma_f32_32x32x16_bf16(paP[ks], bV1, Oacc1, 0, 0, 0);
  }
  // ---- finalize: full row-sum, normalize, write ctx [B,S,H*DH] bf16 ----
  float lfull = lrun + __shfl_xor(lrun, 32);
#pragma unroll
  for (int reg = 0; reg < 16; reg++) {
    const int qrow = (reg & 3) + 8 * (reg >> 2) + 4 * hi;
    float linv = __builtin_amdgcn_rcpf(__shfl(lfull, qrow));
    size_t base = ((size_t)b * 2048 + qb0 + qrow) * 1024 + h * 64;
    ctx[base + c5]      = __float2bfloat16(Oacc0[reg] * linv);
    ctx[base + 32 + c5] = __float2bfloat16(Oacc1[reg] * linv);
  }
}

// ---------------- launch ----------------

extern "C" void kernel_launch(void* const* d_in, const int* in_sizes, int n_in,
                              void* d_out, int out_size, void* d_ws, size_t ws_size,
                              hipStream_t stream) {
  const float* x  = (const float*)d_in[0];
  const float* y  = (const float*)d_in[1];
  const float* Wq = (const float*)d_in[2];
  const float* Wk = (const float*)d_in[3];
  const float* Wv = (const float*)d_in[4];
  const float* Wo = (const float*)d_in[5];
  const float* bo = (const float*)d_in[6];
  const int* amask = (const int*)d_in[7];
  float* out = (float*)d_out;

  char* ws = (char*)d_ws;
  bf16* xb = (bf16*)ws;                              // 16 MB  (later reused as ctx)
  bf16* yb = (bf16*)(ws + 16777216);                 // 16 MB
  bf16* WT = (bf16*)(ws + 33554432);                 // 4 x 2 MB, order q,k,v,o
  bf16* Qb = (bf16*)(ws + 41943040);                 // 16 MB  [B,H,S,64]  (C1-scaled)
  bf16* Kb = (bf16*)(ws + 58720256);                 // 16 MB  [B,H,S,64]
  bf16* Vt = (bf16*)(ws + 75497472);                 // 16 MB  [B,H,64,S]
  unsigned long long* mbits = (unsigned long long*)(ws + 92274688);  // 2 MB
  bf16* ctx = xb;  // alias: xb dead after K projection

  conv_bf16<<<8192, 256, 0, stream>>>(x, xb, 2097152);
  conv_bf16<<<8192, 256, 0, stream>>>(y, yb, 2097152);
  transpose_w<<<dim3(32, 32, 4), dim3(32, 8), 0, stream>>>(Wq, Wk, Wv, Wo, WT);
  maskpack<<<65536, 256, 0, stream>>>(amask, mbits);

  dim3 gg(64, 8);
  gemm_bt<4><<<gg, 256, 0, stream>>>(xb, WT + 0 * 1048576, Qb, nullptr);  // Q (C1-scaled)
  gemm_bt<0><<<gg, 256, 0, stream>>>(xb, WT + 1 * 1048576, Kb, nullptr);  // K
  gemm_bt<1><<<gg, 256, 0, stream>>>(yb, WT + 2 * 1048576, Vt, nullptr);  // V^T

  attn_kernel<<<1024, 256, 0, stream>>>(Qb, Kb, Vt, mbits, ctx);

  gemm_bt<2><<<gg, 256, 0, stream>>>(ctx, WT + 3 * 1048576, out, bo);
}